// Round 7
// baseline (300.911 us; speedup 1.0000x reference)
//
#include <hip/hip_runtime.h>

// SelfAttnBlock: BN -> QKV 1x1conv -> full 4096x4096 attention (flash-style,
// never materialized) -> 1x1 conv -> residual.  MI355X gfx950.
//
// R7 design notes (counter-driven):
//  - R6 confirmed async shared staging theory: 78us, MfmaUtil 37%, no spill.
//  - k_attn: V un-staged (per-lane global loads, issued at step top, consumed
//    at PV -> slack hides L2 latency; L2 has 10x headroom). LDS 64->48KB ->
//    3 blocks/CU (launch_bounds(256,3), VGPR ~120 < 170: no spill).
//    SPLIT=4 -> grid 1024 so 3 blocks/CU actually dispatched.
//  - k_qkv: Q/K stores coalesced via padded LDS transpose tile ([64][68] u16;
//    write banks 2-way free, readout 16B/lane full 128B lines). Same values.
//  - Numerics identical to R2..R6 (absmax 0.015625): QK bf16 hi/lo (6 MFMAs),
//    P/V single bf16, no-max softmax in exp2 domain, f32 atomic partials.

#define HW 4096
#define CC 64
#define NBATCH 8
#define SPLIT 4
#define TSTEPS 16  // 64-key steps per block (1024 keys)
// 0.125 * log2(e): fold attention scale + exp->exp2 conversion into Q
#define QSCALE 0.18033688011112042f

using f32x4 = __attribute__((ext_vector_type(4))) float;
using bf16x8 = __attribute__((ext_vector_type(8))) short;
using u32x2 = __attribute__((ext_vector_type(2))) unsigned int;
typedef unsigned short u16;
typedef unsigned int u32;

#if __has_builtin(__builtin_amdgcn_exp2f)
#define EXP2F(v) __builtin_amdgcn_exp2f(v)
#else
#define EXP2F(v) exp2f(v)
#endif

#define MFMA16(a, b, c) __builtin_amdgcn_mfma_f32_16x16x32_bf16(a, b, c, 0, 0, 0)
#define GLDS(gsrc, ldst)                                              \
  __builtin_amdgcn_global_load_lds(                                   \
      (const __attribute__((address_space(1))) void*)(gsrc),          \
      (__attribute__((address_space(3))) void*)(ldst), 16, 0, 0)

__device__ __forceinline__ u16 f2bf(float v) {  // RNE f32->bf16
  u32 u = __float_as_uint(v);
  return (u16)((u + 0x7fffu + ((u >> 16) & 1u)) >> 16);
}
__device__ __forceinline__ float bf2f(u16 h) {
  return __uint_as_float(((u32)h) << 16);
}
__device__ __forceinline__ u32 cvtpk_bf16(float lo, float hi) {  // RNE pack
  u32 r;
  asm("v_cvt_pk_bf16_f32 %0, %1, %2" : "=v"(r) : "v"(lo), "v"(hi));
  return r;
}

// ---------- kernel 1: BN partial sums (per (n,c) plane) -> atomics into SACC
__global__ __launch_bounds__(256) void k_stats1(const float* __restrict__ x,
                                                float* __restrict__ SACC) {
  const int n = blockIdx.x >> 6;
  const int c = blockIdx.x & 63;
  const int tid = threadIdx.x;
  const float* xp = x + ((size_t)n * CC + c) * HW;
  float s1 = 0.f, s2 = 0.f;
#pragma unroll
  for (int i = tid; i < HW; i += 256) {
    const float v = xp[i];
    s1 += v;
    s2 += v * v;
  }
#pragma unroll
  for (int m = 1; m <= 32; m <<= 1) {
    s1 += __shfl_xor(s1, m);
    s2 += __shfl_xor(s2, m);
  }
  __shared__ float r1[4], r2[4];
  const int w = tid >> 6;
  if ((tid & 63) == 0) { r1[w] = s1; r2[w] = s2; }
  __syncthreads();
  if (tid == 0) {
    unsafeAtomicAdd(SACC + c, r1[0] + r1[1] + r1[2] + r1[3]);
    unsafeAtomicAdd(SACC + CC + c, r2[0] + r2[1] + r2[2] + r2[3]);
  }
}

// ---------- kernel 2: fused BN-apply + Q/K/V 1x1 convs + bf16 hi/lo quantize
// outputs: QH/QL/KH/KL as [n][hw][c] bf16 ; V as [n][c][hw] bf16
__device__ __forceinline__ void mm16(const float* __restrict__ W,
                                     const float* __restrict__ B,
                                     const float* xcol, int o0, float scale,
                                     float* outv) {
#pragma unroll
  for (int oo = 0; oo < 16; ++oo) {
    const int o = o0 + oo;
    float a = B[o];  // o wave-uniform -> SGPR scalar load
#pragma unroll
    for (int c = 0; c < CC; ++c) a = fmaf(W[o * CC + c], xcol[c], a);
    outv[oo] = a * scale;
  }
}

__global__ __launch_bounds__(256) void k_qkv(
    const float* __restrict__ x, const float* __restrict__ SACC,
    const float* __restrict__ gamma, const float* __restrict__ beta,
    const float* __restrict__ wq, const float* __restrict__ bq,
    const float* __restrict__ wk, const float* __restrict__ bk,
    const float* __restrict__ wv, const float* __restrict__ bv,
    u16* __restrict__ QH, u16* __restrict__ QL, u16* __restrict__ KH,
    u16* __restrict__ KL, u16* __restrict__ V) {
  const int n = blockIdx.x >> 6;
  const int i0 = (blockIdx.x & 63) << 6;
  __shared__ float xn[CC][64];
  __shared__ float sa[CC], sb[CC];
  __shared__ u16 TH[64][68];  // padded transpose tiles (2-way banks, free)
  __shared__ u16 TL[64][68];
  const int tid = threadIdx.x;
  if (tid < CC) {  // BN a,b from accumulated stats (biased var, eps=1e-5)
    const float inv = 1.0f / (float)(NBATCH * HW);
    const float mean = SACC[tid] * inv;
    const float var = SACC[CC + tid] * inv - mean * mean;
    const float a = rsqrtf(var + 1e-5f) * gamma[tid];
    sa[tid] = a;
    sb[tid] = beta[tid] - mean * a;
  }
  __syncthreads();
  {
    const int p = tid & 63;
    const int c0 = (tid >> 6) << 4;
    const float* xp = x + (size_t)n * CC * HW + i0 + p;
#pragma unroll
    for (int cc = 0; cc < 16; ++cc) {
      const int c = c0 + cc;
      xn[c][p] = fmaf(xp[(size_t)c * HW], sa[c], sb[c]);
    }
  }
  __syncthreads();
  const int w = __builtin_amdgcn_readfirstlane(tid >> 6);
  const int p = tid & 63;
  float xcol[CC];
#pragma unroll
  for (int c = 0; c < CC; ++c) xcol[c] = xn[c][p];

  const size_t rowbase = (size_t)n * HW + i0;
  u32* const th32 = (u32*)&TH[0][0];
  u32* const tl32 = (u32*)&TL[0][0];
  const int wb32 = (p * 68 + w * 16) >> 1;  // this thread's write slot (u32)
  const int r = tid >> 2;                   // readout: row
  const int q4 = tid & 3;                   // readout: 16-ch chunk
  const int rb32 = (r * 68 + q4 * 16) >> 1;

  float v16[16];
#pragma unroll
  for (int conv = 0; conv < 2; ++conv) {
    if (conv == 0)
      mm16(wq, bq, xcol, w * 16, QSCALE, v16);
    else
      mm16(wk, bk, xcol, w * 16, 1.0f, v16);
    // split hi/lo -> LDS tiles
#pragma unroll
    for (int e = 0; e < 8; ++e) {
      const float v0 = v16[2 * e], v1 = v16[2 * e + 1];
      const u16 h0 = f2bf(v0), h1 = f2bf(v1);
      th32[wb32 + e] = (u32)h0 | ((u32)h1 << 16);
      tl32[wb32 + e] =
          (u32)f2bf(v0 - bf2f(h0)) | ((u32)f2bf(v1 - bf2f(h1)) << 16);
    }
    __syncthreads();
    // readout: thread = (row r, chunk q4): 32B contiguous -> coalesced lines
    {
      u16* const dh = (conv == 0 ? QH : KH) + (rowbase + r) * CC + q4 * 16;
      u16* const dl = (conv == 0 ? QL : KL) + (rowbase + r) * CC + q4 * 16;
      const u32x2 a0 = *(const u32x2*)&th32[rb32];
      const u32x2 a1 = *(const u32x2*)&th32[rb32 + 2];
      const u32x2 a2 = *(const u32x2*)&th32[rb32 + 4];
      const u32x2 a3 = *(const u32x2*)&th32[rb32 + 6];
      *(uint4*)dh = make_uint4(a0[0], a0[1], a1[0], a1[1]);
      *(uint4*)(dh + 8) = make_uint4(a2[0], a2[1], a3[0], a3[1]);
      const u32x2 b0 = *(const u32x2*)&tl32[rb32];
      const u32x2 b1 = *(const u32x2*)&tl32[rb32 + 2];
      const u32x2 b2 = *(const u32x2*)&tl32[rb32 + 4];
      const u32x2 b3 = *(const u32x2*)&tl32[rb32 + 6];
      *(uint4*)dl = make_uint4(b0[0], b0[1], b1[0], b1[1]);
      *(uint4*)(dl + 8) = make_uint4(b2[0], b2[1], b3[0], b3[1]);
    }
    __syncthreads();  // free tiles for next conv
  }
  // V: [n][c][hw] scalar stores are lane-contiguous (coalesced already)
  mm16(wv, bv, xcol, w * 16, 1.0f, v16);
#pragma unroll
  for (int oo = 0; oo < 16; ++oo)
    V[((size_t)n * CC + w * 16 + oo) * HW + i0 + p] = f2bf(v16[oo]);
}

// ---------- kernel 3: flash attention partial; 4 waves x 32 q-rows.
// K hi/lo staged to LDS (global_load_lds dbuf, wave-shared); V per-lane from
// global, issued at step top (slack hides L2 latency).  3 blocks/CU.
__global__ __launch_bounds__(256, 3) void k_attn(
    const u16* __restrict__ QH, const u16* __restrict__ QL,
    const u16* __restrict__ KH, const u16* __restrict__ KL,
    const u16* __restrict__ V, float* __restrict__ RES,
    float* __restrict__ Z) {
  // bid&7 = n -> all blocks of batch n on one XCD (K/V ~3MB ~ 4MB L2)
  const int bid = blockIdx.x;
  const int n = bid & 7;
  const int qt = (bid >> 3) & 31;
  const int s = bid >> 8;  // key-range split 0..3
  const int tid = threadIdx.x;
  const int w = tid >> 6;
  const int l = tid & 63;
  const int l15 = l & 15;
  const int lg = l >> 4;
  const int qw0 = qt * 128 + w * 32;  // this wave's first q-row
  const int key0 = s * (TSTEPS * 64);

  __shared__ alignas(16) u16 KHs[2][64][64];  // [buf][key][ch]   8KB each
  __shared__ alignas(16) u16 KLs[2][64][64];
  __shared__ alignas(16) u16 P[4][32][64];    // per-wave private

  // ---- staging: 16 x 1KB lines/t-step; wave w stages lines w*4..w*4+3.
  // LDS linear; global src pre-swizzled so a (row&7)<<4 byte-XOR read works.
  const int lr8 = l >> 3;
  const u32 eoff = (u32)(((l & 7) * 8) ^ (lr8 << 3));  // u16 units
  const u16* sp[4];
  u16* d0[4];
  u16* d1[4];
#pragma unroll
  for (int c = 0; c < 4; ++c) {
    const int idx = w * 4 + c;
    const int tile = idx >> 3;
    const int j = idx & 7;
    const int lrow = j * 8 + lr8;
    if (tile == 0) {
      sp[c] = KH + ((size_t)n * HW + key0 + lrow) * CC + eoff;
      d0[c] = &KHs[0][j * 8][0];
      d1[c] = &KHs[1][j * 8][0];
    } else {
      sp[c] = KL + ((size_t)n * HW + key0 + lrow) * CC + eoff;
      d0[c] = &KLs[0][j * 8][0];
      d1[c] = &KLs[1][j * 8][0];
    }
  }
  auto stage = [&](int bufsel) {
#pragma unroll
    for (int c = 0; c < 4; ++c) {
      GLDS(sp[c], bufsel ? d1[c] : d0[c]);
      sp[c] += (size_t)64 * CC;
    }
  };

  // resident Q frags: lane holds Q[qw0+qb*16+l15][m*32+lg*8 .. +8] (hi/lo)
  bf16x8 qh[2][2], ql[2][2];
  {
    const size_t qbase = ((size_t)n * HW + qw0 + l15) * CC + lg * 8;
#pragma unroll
    for (int qb = 0; qb < 2; ++qb)
#pragma unroll
      for (int m = 0; m < 2; ++m) {
        const size_t off = qbase + (size_t)qb * 16 * CC + m * 32;
        qh[qb][m] = *(const bf16x8*)(QH + off);
        ql[qb][m] = *(const bf16x8*)(QL + off);
      }
  }

  f32x4 acc[2][4];
#pragma unroll
  for (int qb = 0; qb < 2; ++qb)
#pragma unroll
    for (int chb = 0; chb < 4; ++chb)
      acc[qb][chb] = (f32x4){0.f, 0.f, 0.f, 0.f};
  float zacc[2] = {0.f, 0.f};

  // V B-frag base: lane reads V[chb*16+l15][key + m2*32 + lg*8 ..]
  const u16* vp = V + ((size_t)n * CC + l15) * HW + key0 + lg * 8;

  stage(0);  // t=0 -> buf0
  asm volatile("s_waitcnt vmcnt(0)\n\ts_barrier" ::: "memory");

  const int swz = (l15 & 7) << 4;  // byte-XOR within 128B row
  char* const Pw = (char*)&P[w][0][0];

#pragma unroll 1
  for (int t = 0; t < TSTEPS; ++t) {
    const int buf = t & 1;
    // early-issue V(t): consumed at PV (~700cyc later) -> latency hidden
    bf16x8 vb[2][4];
#pragma unroll
    for (int m2 = 0; m2 < 2; ++m2)
#pragma unroll
      for (int chb = 0; chb < 4; ++chb)
        vb[m2][chb] =
            *(const bf16x8*)(vp + (size_t)chb * 16 * HW + m2 * 32);
    if (t + 1 < TSTEPS) stage(buf ^ 1);  // async, lands before next barrier
    const char* khb = (const char*)&KHs[buf][0][0];
    const char* klb = (const char*)&KLs[buf][0][0];

    // ---- QK phase: S^T = K*Q, hi/lo correction (drop Kl*Ql)
    f32x4 sc[2][4];
#pragma unroll
    for (int kb = 0; kb < 4; ++kb) {
      const int rb = (kb * 16 + l15) * 128;
      const int c0 = (lg * 16) ^ swz;
      const int c1 = (64 + lg * 16) ^ swz;
      const bf16x8 kh0 = *(const bf16x8*)(khb + rb + c0);
      const bf16x8 kh1 = *(const bf16x8*)(khb + rb + c1);
      const bf16x8 kl0 = *(const bf16x8*)(klb + rb + c0);
      const bf16x8 kl1 = *(const bf16x8*)(klb + rb + c1);
      __builtin_amdgcn_s_setprio(1);
#pragma unroll
      for (int qb = 0; qb < 2; ++qb) {
        f32x4 s4 = {0.f, 0.f, 0.f, 0.f};
        s4 = MFMA16(kh0, qh[qb][0], s4);
        s4 = MFMA16(kh1, qh[qb][1], s4);
        s4 = MFMA16(kh0, ql[qb][0], s4);
        s4 = MFMA16(kh1, ql[qb][1], s4);
        s4 = MFMA16(kl0, qh[qb][0], s4);
        s4 = MFMA16(kl1, qh[qb][1], s4);
        sc[qb][kb] = s4;
      }
      __builtin_amdgcn_s_setprio(0);
    }
    // ---- softmax numerator + P store (private region, swizzled)
#pragma unroll
    for (int qb = 0; qb < 2; ++qb) {
      char* const prow = Pw + (qb * 16 + l15) * 128;
      float zs = 0.f;
#pragma unroll
      for (int kb = 0; kb < 4; ++kb) {
        const float p0 = EXP2F(sc[qb][kb][0]);
        const float p1 = EXP2F(sc[qb][kb][1]);
        const float p2 = EXP2F(sc[qb][kb][2]);
        const float p3 = EXP2F(sc[qb][kb][3]);
        zs += (p0 + p1) + (p2 + p3);
        const u32x2 pk = {cvtpk_bf16(p0, p1), cvtpk_bf16(p2, p3)};
        *(u32x2*)(prow + ((kb * 32 + lg * 8) ^ swz)) = pk;
      }
      zacc[qb] += zs;
    }
    // ---- PV phase (same-wave P read-back; V from regs)
#pragma unroll
    for (int m2 = 0; m2 < 2; ++m2) {
      __builtin_amdgcn_s_setprio(1);
#pragma unroll
      for (int qb = 0; qb < 2; ++qb) {
        const bf16x8 pa = *(const bf16x8*)(
            Pw + (qb * 16 + l15) * 128 + ((m2 * 64 + lg * 16) ^ swz));
#pragma unroll
        for (int chb = 0; chb < 4; ++chb)
          acc[qb][chb] = MFMA16(pa, vb[m2][chb], acc[qb][chb]);
      }
      __builtin_amdgcn_s_setprio(0);
    }
    vp += 64;
    // barrier: wait staged loads (vmcnt) + own LDS ops; single sync/step
    asm volatile("s_waitcnt vmcnt(0) lgkmcnt(0)\n\ts_barrier" ::: "memory");
  }

  // z partials: sum over key-groups (lg) then atomic
#pragma unroll
  for (int qb = 0; qb < 2; ++qb) {
    zacc[qb] += __shfl_xor(zacc[qb], 16);
    zacc[qb] += __shfl_xor(zacc[qb], 32);
  }
  if (l < 16) {
    unsafeAtomicAdd(Z + (size_t)n * HW + qw0 + l, zacc[0]);
    unsafeAtomicAdd(Z + (size_t)n * HW + qw0 + 16 + l, zacc[1]);
  }
  // acc partials -> RES atomics (unnormalized; k_out divides by Z)
  float* resn = RES + ((size_t)n * HW + qw0) * CC;
#pragma unroll
  for (int qb = 0; qb < 2; ++qb)
#pragma unroll
    for (int r = 0; r < 4; ++r) {
      const int row = qb * 16 + lg * 4 + r;
#pragma unroll
      for (int chb = 0; chb < 4; ++chb)
        unsafeAtomicAdd(resn + (size_t)row * CC + chb * 16 + l15,
                        acc[qb][chb][r]);
    }
}

// ---------- kernel 4: out = x + wo @ (res/z reshaped) + bo
// res[n] flat [i][ch] == [c2][h2][w2]; conv mixes c2.  Row i = c2*64 + (j>>6).
__global__ __launch_bounds__(256) void k_out(const float* __restrict__ RES,
                                             const float* __restrict__ Z,
                                             const float* __restrict__ x,
                                             const float* __restrict__ wo,
                                             const float* __restrict__ bo,
                                             float* __restrict__ out) {
  const int n = blockIdx.x >> 6;
  const int j = ((blockIdx.x & 63) << 6) + (threadIdx.x & 63);  // h2*64+w2
  const int oq = __builtin_amdgcn_readfirstlane(threadIdx.x >> 6);
  const float* rn = RES + (size_t)n * HW * CC;
  const float* zb = Z + (size_t)n * HW;
  const int jh = j >> 6;
  float rcol[CC];
#pragma unroll
  for (int c2 = 0; c2 < CC; ++c2)
    rcol[c2] = rn[(size_t)c2 * HW + j] * (1.0f / zb[c2 * 64 + jh]);
  const size_t xb = (size_t)n * CC * HW;
  for (int o = oq * 16; o < oq * 16 + 16; ++o) {
    float sacc = bo[o];
#pragma unroll
    for (int c2 = 0; c2 < CC; ++c2)
      sacc = fmaf(wo[o * CC + c2], rcol[c2], sacc);
    out[xb + (size_t)o * HW + j] = x[xb + (size_t)o * HW + j] + sacc;
  }
}

extern "C" void kernel_launch(void* const* d_in, const int* in_sizes, int n_in,
                              void* d_out, int out_size, void* d_ws,
                              size_t ws_size, hipStream_t stream) {
  const float* x = (const float*)d_in[0];
  const float* gamma = (const float*)d_in[1];
  const float* beta = (const float*)d_in[2];
  const float* wq = (const float*)d_in[3];
  const float* bq = (const float*)d_in[4];
  const float* wk = (const float*)d_in[5];
  const float* bk = (const float*)d_in[6];
  const float* wv = (const float*)d_in[7];
  const float* bv = (const float*)d_in[8];
  const float* wo = (const float*)d_in[9];
  const float* bo = (const float*)d_in[10];
  float* out = (float*)d_out;

  char* ws = (char*)d_ws;
  // layout: [SACC 1KB][Z 128KB][RES 8MB][QH|QL|KH|KL|V 5x4MB]  (~28.5MB)
  float* SACC = (float*)ws;
  float* Z = (float*)(ws + 1024);
  float* RES = (float*)(ws + 1024 + (size_t)NBATCH * HW * 4);
  const size_t INIT_BYTES =
      1024 + (size_t)NBATCH * HW * 4 + (size_t)NBATCH * HW * CC * 4;
  const size_t ARR = (size_t)NBATCH * HW * CC;
  u16* QH = (u16*)(ws + INIT_BYTES);
  u16* QL = QH + ARR;
  u16* KH = QL + ARR;
  u16* KL = KH + ARR;
  u16* V = KL + ARR;

  hipMemsetAsync(ws, 0, INIT_BYTES, stream);  // zero SACC, Z, RES
  hipLaunchKernelGGL(k_stats1, dim3(512), dim3(256), 0, stream, x, SACC);
  hipLaunchKernelGGL(k_qkv, dim3(512), dim3(256), 0, stream, x, SACC, gamma,
                     beta, wq, bq, wk, bk, wv, bv, QH, QL, KH, KL, V);
  hipLaunchKernelGGL(k_attn, dim3(1024), dim3(256), 0, stream, QH, QL, KH, KL,
                     V, RES, Z);
  hipLaunchKernelGGL(k_out, dim3(512), dim3(256), 0, stream, RES, Z, x, wo, bo,
                     out);
}

// Round 8
// 248.330 us; speedup vs baseline: 1.2117x; 1.2117x over previous
//
#include <hip/hip_runtime.h>

// SelfAttnBlock: BN -> QKV 1x1conv -> full 4096x4096 attention (flash-style,
// never materialized) -> 1x1 conv -> residual.  MI355X gfx950.
//
// R8 design notes (counter-driven):
//  - R7 post-mortem: V un-staging sank to PV (VGPR 84 -> compiler refused the
//    +32-reg live range) -> latency exposed, MfmaUtil 18%. Reverted.
//  - Base = R6 (78us proven: wave-shared global_load_lds dbuf staging for
//    KH/KL/V, private-P LDS, single vmcnt+lgkm barrier per step).
//  - Change: 64 q-rows/wave (qb 2->4). MFMA/step doubles, K/V LDS reads per
//    step unchanged -> LDS-pipe cost per unit work halves. Model: MFMA 33us
//    vs LDS 29us per CU -> MFMA-bound (R6 was LDS-bound at 47us).
//  - LDS 80KB/block (K 32 + V 16 + P 32) -> exactly 2 blocks/CU (160KB).
//    VGPR peak ~230 < 256 cap at 2 waves/SIMD (launch_bounds(256,2)).
//  - Grid 512 = 8n x 16 qtiles(256 rows) x SPLIT=4 (TSTEPS=16).
//  - Numerics identical to R2..R7 (absmax 0.015625): QK bf16 hi/lo (6 MFMAs),
//    P/V single bf16, no-max softmax in exp2 domain, f32 atomic partials.

#define HW 4096
#define CC 64
#define NBATCH 8
#define SPLIT 4
#define TSTEPS 16  // 64-key steps per block (1024 keys)
// 0.125 * log2(e): fold attention scale + exp->exp2 conversion into Q
#define QSCALE 0.18033688011112042f

using f32x4 = __attribute__((ext_vector_type(4))) float;
using bf16x8 = __attribute__((ext_vector_type(8))) short;
using u32x2 = __attribute__((ext_vector_type(2))) unsigned int;
typedef unsigned short u16;
typedef unsigned int u32;

#if __has_builtin(__builtin_amdgcn_exp2f)
#define EXP2F(v) __builtin_amdgcn_exp2f(v)
#else
#define EXP2F(v) exp2f(v)
#endif

#define MFMA16(a, b, c) __builtin_amdgcn_mfma_f32_16x16x32_bf16(a, b, c, 0, 0, 0)
#define GLDS(gsrc, ldst)                                              \
  __builtin_amdgcn_global_load_lds(                                   \
      (const __attribute__((address_space(1))) void*)(gsrc),          \
      (__attribute__((address_space(3))) void*)(ldst), 16, 0, 0)

__device__ __forceinline__ u16 f2bf(float v) {  // RNE f32->bf16
  u32 u = __float_as_uint(v);
  return (u16)((u + 0x7fffu + ((u >> 16) & 1u)) >> 16);
}
__device__ __forceinline__ float bf2f(u16 h) {
  return __uint_as_float(((u32)h) << 16);
}
__device__ __forceinline__ u32 cvtpk_bf16(float lo, float hi) {  // RNE pack
  u32 r;
  asm("v_cvt_pk_bf16_f32 %0, %1, %2" : "=v"(r) : "v"(lo), "v"(hi));
  return r;
}

// ---------- kernel 1: BN partial sums (per (n,c) plane) -> atomics into SACC
__global__ __launch_bounds__(256) void k_stats1(const float* __restrict__ x,
                                                float* __restrict__ SACC) {
  const int n = blockIdx.x >> 6;
  const int c = blockIdx.x & 63;
  const int tid = threadIdx.x;
  const float* xp = x + ((size_t)n * CC + c) * HW;
  float s1 = 0.f, s2 = 0.f;
#pragma unroll
  for (int i = tid; i < HW; i += 256) {
    const float v = xp[i];
    s1 += v;
    s2 += v * v;
  }
#pragma unroll
  for (int m = 1; m <= 32; m <<= 1) {
    s1 += __shfl_xor(s1, m);
    s2 += __shfl_xor(s2, m);
  }
  __shared__ float r1[4], r2[4];
  const int w = tid >> 6;
  if ((tid & 63) == 0) { r1[w] = s1; r2[w] = s2; }
  __syncthreads();
  if (tid == 0) {
    unsafeAtomicAdd(SACC + c, r1[0] + r1[1] + r1[2] + r1[3]);
    unsafeAtomicAdd(SACC + CC + c, r2[0] + r2[1] + r2[2] + r2[3]);
  }
}

// ---------- kernel 2: fused BN-apply + Q/K/V 1x1 convs + bf16 hi/lo quantize
// outputs: QH/QL/KH/KL as [n][hw][c] bf16 ; V as [n][c][hw] bf16
__device__ __forceinline__ void mm16(const float* __restrict__ W,
                                     const float* __restrict__ B,
                                     const float* xcol, int o0, float scale,
                                     float* outv) {
#pragma unroll
  for (int oo = 0; oo < 16; ++oo) {
    const int o = o0 + oo;
    float a = B[o];  // o wave-uniform -> SGPR scalar load
#pragma unroll
    for (int c = 0; c < CC; ++c) a = fmaf(W[o * CC + c], xcol[c], a);
    outv[oo] = a * scale;
  }
}

__global__ __launch_bounds__(256) void k_qkv(
    const float* __restrict__ x, const float* __restrict__ SACC,
    const float* __restrict__ gamma, const float* __restrict__ beta,
    const float* __restrict__ wq, const float* __restrict__ bq,
    const float* __restrict__ wk, const float* __restrict__ bk,
    const float* __restrict__ wv, const float* __restrict__ bv,
    u16* __restrict__ QH, u16* __restrict__ QL, u16* __restrict__ KH,
    u16* __restrict__ KL, u16* __restrict__ V) {
  const int n = blockIdx.x >> 6;
  const int i0 = (blockIdx.x & 63) << 6;
  __shared__ float xn[CC][64];
  __shared__ float sa[CC], sb[CC];
  __shared__ u16 TH[64][68];  // padded transpose tiles (2-way banks, free)
  __shared__ u16 TL[64][68];
  const int tid = threadIdx.x;
  if (tid < CC) {  // BN a,b from accumulated stats (biased var, eps=1e-5)
    const float inv = 1.0f / (float)(NBATCH * HW);
    const float mean = SACC[tid] * inv;
    const float var = SACC[CC + tid] * inv - mean * mean;
    const float a = rsqrtf(var + 1e-5f) * gamma[tid];
    sa[tid] = a;
    sb[tid] = beta[tid] - mean * a;
  }
  __syncthreads();
  {
    const int p = tid & 63;
    const int c0 = (tid >> 6) << 4;
    const float* xp = x + (size_t)n * CC * HW + i0 + p;
#pragma unroll
    for (int cc = 0; cc < 16; ++cc) {
      const int c = c0 + cc;
      xn[c][p] = fmaf(xp[(size_t)c * HW], sa[c], sb[c]);
    }
  }
  __syncthreads();
  const int w = __builtin_amdgcn_readfirstlane(tid >> 6);
  const int p = tid & 63;
  float xcol[CC];
#pragma unroll
  for (int c = 0; c < CC; ++c) xcol[c] = xn[c][p];

  const size_t rowbase = (size_t)n * HW + i0;
  u32* const th32 = (u32*)&TH[0][0];
  u32* const tl32 = (u32*)&TL[0][0];
  const int wb32 = (p * 68 + w * 16) >> 1;  // this thread's write slot (u32)
  const int r = tid >> 2;                   // readout: row
  const int q4 = tid & 3;                   // readout: 16-ch chunk
  const int rb32 = (r * 68 + q4 * 16) >> 1;

  float v16[16];
#pragma unroll
  for (int conv = 0; conv < 2; ++conv) {
    if (conv == 0)
      mm16(wq, bq, xcol, w * 16, QSCALE, v16);
    else
      mm16(wk, bk, xcol, w * 16, 1.0f, v16);
    // split hi/lo -> LDS tiles
#pragma unroll
    for (int e = 0; e < 8; ++e) {
      const float v0 = v16[2 * e], v1 = v16[2 * e + 1];
      const u16 h0 = f2bf(v0), h1 = f2bf(v1);
      th32[wb32 + e] = (u32)h0 | ((u32)h1 << 16);
      tl32[wb32 + e] =
          (u32)f2bf(v0 - bf2f(h0)) | ((u32)f2bf(v1 - bf2f(h1)) << 16);
    }
    __syncthreads();
    // readout: thread = (row r, chunk q4): 32B contiguous -> coalesced lines
    {
      u16* const dh = (conv == 0 ? QH : KH) + (rowbase + r) * CC + q4 * 16;
      u16* const dl = (conv == 0 ? QL : KL) + (rowbase + r) * CC + q4 * 16;
      const u32x2 a0 = *(const u32x2*)&th32[rb32];
      const u32x2 a1 = *(const u32x2*)&th32[rb32 + 2];
      const u32x2 a2 = *(const u32x2*)&th32[rb32 + 4];
      const u32x2 a3 = *(const u32x2*)&th32[rb32 + 6];
      *(uint4*)dh = make_uint4(a0[0], a0[1], a1[0], a1[1]);
      *(uint4*)(dh + 8) = make_uint4(a2[0], a2[1], a3[0], a3[1]);
      const u32x2 b0 = *(const u32x2*)&tl32[rb32];
      const u32x2 b1 = *(const u32x2*)&tl32[rb32 + 2];
      const u32x2 b2 = *(const u32x2*)&tl32[rb32 + 4];
      const u32x2 b3 = *(const u32x2*)&tl32[rb32 + 6];
      *(uint4*)dl = make_uint4(b0[0], b0[1], b1[0], b1[1]);
      *(uint4*)(dl + 8) = make_uint4(b2[0], b2[1], b3[0], b3[1]);
    }
    __syncthreads();  // free tiles for next conv
  }
  // V: [n][c][hw] scalar stores are lane-contiguous (coalesced already)
  mm16(wv, bv, xcol, w * 16, 1.0f, v16);
#pragma unroll
  for (int oo = 0; oo < 16; ++oo)
    V[((size_t)n * CC + w * 16 + oo) * HW + i0 + p] = f2bf(v16[oo]);
}

// ---------- kernel 3: flash attention partial; 4 waves x 64 q-rows.
// KH/KL/V staged to LDS (global_load_lds dbuf, wave-shared). 2 blocks/CU.
__global__ __launch_bounds__(256, 2) void k_attn(
    const u16* __restrict__ QH, const u16* __restrict__ QL,
    const u16* __restrict__ KH, const u16* __restrict__ KL,
    const u16* __restrict__ V, float* __restrict__ RES,
    float* __restrict__ Z) {
  // bid&7 = n -> all blocks of batch n on one XCD (K/V+Q ~2.5MB < 4MB L2)
  const int bid = blockIdx.x;
  const int n = bid & 7;
  const int qt = (bid >> 3) & 15;
  const int s = bid >> 7;  // key-range split 0..3
  const int tid = threadIdx.x;
  const int w = tid >> 6;
  const int l = tid & 63;
  const int l15 = l & 15;
  const int lg = l >> 4;
  const int qw0 = qt * 256 + w * 64;  // this wave's first q-row
  const int key0 = s * (TSTEPS * 64);

  __shared__ alignas(16) u16 KHs[2][64][64];  // [buf][key][ch]   8KB each
  __shared__ alignas(16) u16 KLs[2][64][64];
  __shared__ alignas(16) u16 Vs[2][64][64];   // [buf][ch][key]
  __shared__ alignas(16) u16 P[4][64][64];    // per-wave private (32KB)

  // ---- staging: 24 x 1KB lines/t-step; wave w stages lines w*6..w*6+5.
  // LDS linear; global src pre-swizzled so a (row&7)<<4 byte-XOR read works.
  const int lr8 = l >> 3;
  const u32 eoff = (u32)(((l & 7) * 8) ^ (lr8 << 3));  // u16 units
  const u16* sp[6];
  u16* d0[6];
  u16* d1[6];
  size_t stp[6];
#pragma unroll
  for (int c = 0; c < 6; ++c) {
    const int idx = w * 6 + c;
    const int tile = idx >> 3;
    const int j = idx & 7;
    const int lrow = j * 8 + lr8;
    if (tile == 0) {
      sp[c] = KH + ((size_t)n * HW + key0 + lrow) * CC + eoff;
      stp[c] = (size_t)64 * CC;
      d0[c] = &KHs[0][j * 8][0];
      d1[c] = &KHs[1][j * 8][0];
    } else if (tile == 1) {
      sp[c] = KL + ((size_t)n * HW + key0 + lrow) * CC + eoff;
      stp[c] = (size_t)64 * CC;
      d0[c] = &KLs[0][j * 8][0];
      d1[c] = &KLs[1][j * 8][0];
    } else {
      sp[c] = V + ((size_t)n * CC + lrow) * HW + key0 + eoff;
      stp[c] = 64;
      d0[c] = &Vs[0][j * 8][0];
      d1[c] = &Vs[1][j * 8][0];
    }
  }
  auto stage = [&](int bufsel) {
#pragma unroll
    for (int c = 0; c < 6; ++c) {
      GLDS(sp[c], bufsel ? d1[c] : d0[c]);
      sp[c] += stp[c];
    }
  };

  // resident Q frags: lane holds Q[qw0+qb*16+l15][m*32+lg*8 .. +8] (hi/lo)
  bf16x8 qh[4][2], ql[4][2];
  {
    const size_t qbase = ((size_t)n * HW + qw0 + l15) * CC + lg * 8;
#pragma unroll
    for (int qb = 0; qb < 4; ++qb)
#pragma unroll
      for (int m = 0; m < 2; ++m) {
        const size_t off = qbase + (size_t)qb * 16 * CC + m * 32;
        qh[qb][m] = *(const bf16x8*)(QH + off);
        ql[qb][m] = *(const bf16x8*)(QL + off);
      }
  }

  f32x4 acc[4][4];
#pragma unroll
  for (int qb = 0; qb < 4; ++qb)
#pragma unroll
    for (int chb = 0; chb < 4; ++chb)
      acc[qb][chb] = (f32x4){0.f, 0.f, 0.f, 0.f};
  float zacc[4] = {0.f, 0.f, 0.f, 0.f};

  stage(0);  // t=0 -> buf0
  asm volatile("s_waitcnt vmcnt(0)\n\ts_barrier" ::: "memory");

  const int swz = (l15 & 7) << 4;  // byte-XOR within 128B row
  char* const Pw = (char*)&P[w][0][0];

#pragma unroll 1
  for (int t = 0; t < TSTEPS; ++t) {
    const int buf = t & 1;
    if (t + 1 < TSTEPS) stage(buf ^ 1);  // async, lands before next barrier
    const char* khb = (const char*)&KHs[buf][0][0];
    const char* klb = (const char*)&KLs[buf][0][0];
    const char* vsb = (const char*)&Vs[buf][0][0];

    // ---- QK phase: S^T = K*Q, hi/lo correction (drop Kl*Ql).
    // kb-outer keeps only 16 K regs live; sc[qb][kb] accumulates (64 regs).
    f32x4 sc[4][4];
#pragma unroll
    for (int kb = 0; kb < 4; ++kb) {
      const int rb = (kb * 16 + l15) * 128;
      const int c0 = (lg * 16) ^ swz;
      const int c1 = (64 + lg * 16) ^ swz;
      const bf16x8 kh0 = *(const bf16x8*)(khb + rb + c0);
      const bf16x8 kh1 = *(const bf16x8*)(khb + rb + c1);
      const bf16x8 kl0 = *(const bf16x8*)(klb + rb + c0);
      const bf16x8 kl1 = *(const bf16x8*)(klb + rb + c1);
      __builtin_amdgcn_s_setprio(1);
#pragma unroll
      for (int qb = 0; qb < 4; ++qb) {
        f32x4 s4 = {0.f, 0.f, 0.f, 0.f};
        s4 = MFMA16(kh0, qh[qb][0], s4);
        s4 = MFMA16(kh1, qh[qb][1], s4);
        s4 = MFMA16(kh0, ql[qb][0], s4);
        s4 = MFMA16(kh1, ql[qb][1], s4);
        s4 = MFMA16(kl0, qh[qb][0], s4);
        s4 = MFMA16(kl1, qh[qb][1], s4);
        sc[qb][kb] = s4;
      }
      __builtin_amdgcn_s_setprio(0);
    }
    // ---- softmax numerator + P store (private region, swizzled)
#pragma unroll
    for (int qb = 0; qb < 4; ++qb) {
      char* const prow = Pw + (qb * 16 + l15) * 128;
      float zs = 0.f;
#pragma unroll
      for (int kb = 0; kb < 4; ++kb) {
        const float p0 = EXP2F(sc[qb][kb][0]);
        const float p1 = EXP2F(sc[qb][kb][1]);
        const float p2 = EXP2F(sc[qb][kb][2]);
        const float p3 = EXP2F(sc[qb][kb][3]);
        zs += (p0 + p1) + (p2 + p3);
        const u32x2 pk = {cvtpk_bf16(p0, p1), cvtpk_bf16(p2, p3)};
        *(u32x2*)(prow + ((kb * 32 + lg * 8) ^ swz)) = pk;
      }
      zacc[qb] += zs;
    }
    // ---- PV phase (same-wave P read-back; V from LDS)
#pragma unroll
    for (int m2 = 0; m2 < 2; ++m2) {
      const int cc2 = (m2 * 64 + lg * 16) ^ swz;
      bf16x8 vb[4];
#pragma unroll
      for (int chb = 0; chb < 4; ++chb)
        vb[chb] = *(const bf16x8*)(vsb + (chb * 16 + l15) * 128 + cc2);
      __builtin_amdgcn_s_setprio(1);
#pragma unroll
      for (int qb = 0; qb < 4; ++qb) {
        const bf16x8 pa = *(const bf16x8*)(Pw + (qb * 16 + l15) * 128 + cc2);
#pragma unroll
        for (int chb = 0; chb < 4; ++chb)
          acc[qb][chb] = MFMA16(pa, vb[chb], acc[qb][chb]);
      }
      __builtin_amdgcn_s_setprio(0);
    }
    // barrier: wait staged loads (vmcnt) + own LDS ops; single sync/step
    asm volatile("s_waitcnt vmcnt(0) lgkmcnt(0)\n\ts_barrier" ::: "memory");
  }

  // z partials: sum over key-groups (lg) then atomic
#pragma unroll
  for (int qb = 0; qb < 4; ++qb) {
    zacc[qb] += __shfl_xor(zacc[qb], 16);
    zacc[qb] += __shfl_xor(zacc[qb], 32);
  }
  if (l < 16) {
#pragma unroll
    for (int qb = 0; qb < 4; ++qb)
      unsafeAtomicAdd(Z + (size_t)n * HW + qw0 + qb * 16 + l, zacc[qb]);
  }
  // acc partials -> RES atomics (unnormalized; k_out divides by Z)
  float* resn = RES + ((size_t)n * HW + qw0) * CC;
#pragma unroll
  for (int qb = 0; qb < 4; ++qb)
#pragma unroll
    for (int r = 0; r < 4; ++r) {
      const int row = qb * 16 + lg * 4 + r;
#pragma unroll
      for (int chb = 0; chb < 4; ++chb)
        unsafeAtomicAdd(resn + (size_t)row * CC + chb * 16 + l15,
                        acc[qb][chb][r]);
    }
}

// ---------- kernel 4: out = x + wo @ (res/z reshaped) + bo
// res[n] flat [i][ch] == [c2][h2][w2]; conv mixes c2.  Row i = c2*64 + (j>>6).
__global__ __launch_bounds__(256) void k_out(const float* __restrict__ RES,
                                             const float* __restrict__ Z,
                                             const float* __restrict__ x,
                                             const float* __restrict__ wo,
                                             const float* __restrict__ bo,
                                             float* __restrict__ out) {
  const int n = blockIdx.x >> 6;
  const int j = ((blockIdx.x & 63) << 6) + (threadIdx.x & 63);  // h2*64+w2
  const int oq = __builtin_amdgcn_readfirstlane(threadIdx.x >> 6);
  const float* rn = RES + (size_t)n * HW * CC;
  const float* zb = Z + (size_t)n * HW;
  const int jh = j >> 6;
  float rcol[CC];
#pragma unroll
  for (int c2 = 0; c2 < CC; ++c2)
    rcol[c2] = rn[(size_t)c2 * HW + j] * (1.0f / zb[c2 * 64 + jh]);
  const size_t xb = (size_t)n * CC * HW;
  for (int o = oq * 16; o < oq * 16 + 16; ++o) {
    float sacc = bo[o];
#pragma unroll
    for (int c2 = 0; c2 < CC; ++c2)
      sacc = fmaf(wo[o * CC + c2], rcol[c2], sacc);
    out[xb + (size_t)o * HW + j] = x[xb + (size_t)o * HW + j] + sacc;
  }
}

extern "C" void kernel_launch(void* const* d_in, const int* in_sizes, int n_in,
                              void* d_out, int out_size, void* d_ws,
                              size_t ws_size, hipStream_t stream) {
  const float* x = (const float*)d_in[0];
  const float* gamma = (const float*)d_in[1];
  const float* beta = (const float*)d_in[2];
  const float* wq = (const float*)d_in[3];
  const float* bq = (const float*)d_in[4];
  const float* wk = (const float*)d_in[5];
  const float* bk = (const float*)d_in[6];
  const float* wv = (const float*)d_in[7];
  const float* bv = (const float*)d_in[8];
  const float* wo = (const float*)d_in[9];
  const float* bo = (const float*)d_in[10];
  float* out = (float*)d_out;

  char* ws = (char*)d_ws;
  // layout: [SACC 1KB][Z 128KB][RES 8MB][QH|QL|KH|KL|V 5x4MB]  (~28.5MB)
  float* SACC = (float*)ws;
  float* Z = (float*)(ws + 1024);
  float* RES = (float*)(ws + 1024 + (size_t)NBATCH * HW * 4);
  const size_t INIT_BYTES =
      1024 + (size_t)NBATCH * HW * 4 + (size_t)NBATCH * HW * CC * 4;
  const size_t ARR = (size_t)NBATCH * HW * CC;
  u16* QH = (u16*)(ws + INIT_BYTES);
  u16* QL = QH + ARR;
  u16* KH = QL + ARR;
  u16* KL = KH + ARR;
  u16* V = KL + ARR;

  hipMemsetAsync(ws, 0, INIT_BYTES, stream);  // zero SACC, Z, RES
  hipLaunchKernelGGL(k_stats1, dim3(512), dim3(256), 0, stream, x, SACC);
  hipLaunchKernelGGL(k_qkv, dim3(512), dim3(256), 0, stream, x, SACC, gamma,
                     beta, wq, bq, wk, bk, wv, bv, QH, QL, KH, KL, V);
  hipLaunchKernelGGL(k_attn, dim3(512), dim3(256), 0, stream, QH, QL, KH, KL,
                     V, RES, Z);
  hipLaunchKernelGGL(k_out, dim3(512), dim3(256), 0, stream, RES, Z, x, wo, bo,
                     out);
}